// Round 18
// baseline (276.228 us; speedup 1.0000x reference)
//
#include <hip/hip_runtime.h>

#define BB 16
#define DD 512
#define TT 4096
#define KK 1024
#define NN (BB*TT)              // 65536 rows
#define RWS 16                  // rows per block (3 blocks/CU target)
#define BT 512                  // 8 waves
#define NW 8
#define MARGIN 1e-3f            // candidate margin (req <=8e-4, 25% slack)
#define CM 6                    // candidate slots per row
#define XLD 516                 // floats per x row (2064 B, 16B-aligned)
#define NPART (NN/RWS)          // 4096 partials

typedef __attribute__((ext_vector_type(8))) short short8v;   // 8 bf16
typedef __attribute__((ext_vector_type(4))) float f32x4;

// ---- bf16 helper (RNE) ----
__device__ __forceinline__ unsigned short f2bf(float f) {
    unsigned int u = __float_as_uint(f);
    unsigned int r = (u + 0x7fffu + ((u >> 16) & 1u)) >> 16;
    return (unsigned short)r;
}

// ---- sortable-float mapping (monotone: f1<f2 <=> u1<u2) ----
__device__ __forceinline__ unsigned int f2sort(float f) {
    unsigned int b = __float_as_uint(f);
    return (b & 0x80000000u) ? ~b : (b | 0x80000000u);
}
__device__ __forceinline__ float sort2f(unsigned int u) {
    unsigned int b = (u & 0x80000000u) ? (u & 0x7fffffffu) : ~u;
    return __uint_as_float(b);
}

// ---- numpy pairwise-sum replication (fp32, squares) — verified passing ----
__device__ __forceinline__ float pw128_sq_strided(const float* a, int stride) {
    float V[16];
    #pragma unroll
    for (int l = 0; l < 16; ++l) {
        float q[8];
        #pragma unroll
        for (int k = 0; k < 8; ++k) {
            float e = a[(l + 16 * k) * stride];
            q[k] = __fmul_rn(e, e);
        }
        V[l] = __fadd_rn(__fadd_rn(__fadd_rn(q[0], q[1]), __fadd_rn(q[2], q[3])),
                         __fadd_rn(__fadd_rn(q[4], q[5]), __fadd_rn(q[6], q[7])));
    }
    float u[8];
    #pragma unroll
    for (int l = 0; l < 8; ++l) u[l] = __fadd_rn(V[l], V[l + 8]);
    float v[4];
    #pragma unroll
    for (int l = 0; l < 4; ++l) v[l] = __fadd_rn(u[l], u[l + 4]);
    return __fadd_rn(__fadd_rn(v[0], v[2]), __fadd_rn(v[1], v[3]));
}
__device__ __forceinline__ float pw512_sq_strided(const float* a, int stride) {
    float p0 = pw128_sq_strided(a, stride);
    float p1 = pw128_sq_strided(a + 128 * stride, stride);
    float p2 = pw128_sq_strided(a + 256 * stride, stride);
    float p3 = pw128_sq_strided(a + 384 * stride, stride);
    return __fadd_rn(__fadd_rn(p0, p1), __fadd_rn(p2, p3));
}

// ---------------- exact ||e||^2 per code row ----------------
__global__ void enorms_exact(const float* __restrict__ E, float* __restrict__ se) {
    int i = blockIdx.x * blockDim.x + threadIdx.x;
    if (i < KK) se[i] = pw512_sq_strided(E + (long)i * DD, 1);
}

// ---------------- pack E (hi bf16) into MFMA B-fragment layout (u32 pairs) --
__global__ void pack_e(const float* __restrict__ E, unsigned short* __restrict__ Bph) {
    int i = blockIdx.x * blockDim.x + threadIdx.x;   // 0 .. KK*DD/2-1
    if (i >= KK * DD / 2) return;
    int c = i >> 8;
    int k = (i & 255) * 2;
    float2 v = *reinterpret_cast<const float2*>(E + ((long)c << 9) + k);
    int lane = (c & 15) + ((k >> 3) & 3) * 16;
    int hw = (((c >> 4) * 16 + (k >> 5)) * 64 + lane) * 8 + (k & 7);
    unsigned int pk = (unsigned int)f2bf(v.x) | ((unsigned int)f2bf(v.y) << 16);
    *reinterpret_cast<unsigned int*>(Bph + hw) = pk;
}

// ---- build bf16-hi A fragment from row-major f32 LDS row (r5/r13-verified) ----
__device__ __forceinline__ short8v build_frag_rm(const float* __restrict__ row, int c0) {
    union { short8v v; unsigned int wd[4]; } u;
    float4 a = *reinterpret_cast<const float4*>(row + c0);
    float4 b = *reinterpret_cast<const float4*>(row + c0 + 4);
    asm("v_cvt_pk_bf16_f32 %0, %1, %2" : "=v"(u.wd[0]) : "v"(a.x), "v"(a.y));
    asm("v_cvt_pk_bf16_f32 %0, %1, %2" : "=v"(u.wd[1]) : "v"(a.z), "v"(a.w));
    asm("v_cvt_pk_bf16_f32 %0, %1, %2" : "=v"(u.wd[2]) : "v"(b.x), "v"(b.y));
    asm("v_cvt_pk_bf16_f32 %0, %1, %2" : "=v"(u.wd[3]) : "v"(b.z), "v"(b.w));
    return u.v;
}

// =============== fused (3 blocks/CU target): filter + replay + output =====
__global__ __launch_bounds__(BT)
void vq_fused(const float* __restrict__ x, const float* __restrict__ E,
              const unsigned short* __restrict__ Bph,
              const float* __restrict__ se,
              double* __restrict__ partials, float* __restrict__ out) {
    __shared__ __align__(16) float xsf[RWS * XLD];   // 33,024 B row-major [r][d]
    __shared__ unsigned int rowmin[RWS];             // sortable-bits global row min
    __shared__ int   rcnt[RWS];
    __shared__ unsigned short rc[RWS][CM];
    __shared__ unsigned long long rmin[RWS];
    __shared__ float sxs[RWS];
    __shared__ int   fidx[RWS];
    __shared__ int   oflag[RWS];
    __shared__ double wloss[NW];
    __shared__ int   oany;

    const int tid  = threadIdx.x;
    const int w    = tid >> 6;              // 0..7
    const int lane = tid & 63;
    const int blk  = blockIdx.x;
    const int b    = blk >> 8;              // 256 blocks per batch
    const int t0   = (blk & 255) * RWS;
    const long nbase = (long)b * TT + t0;
    const float* xb = x + (long)b * DD * TT + t0;

    if (tid < RWS) {
        rcnt[tid] = 0; rowmin[tid] = 0xFFFFFFFFu; rmin[tid] = ~0ull;
        oflag[tid] = 0; fidx[tid] = -1;
    }
    if (tid == 0) oany = 0;

    // ---- stage: dword loads (lane&15 = row), float4 LDS writes (2-way free) ----
    {
        const int r  = lane & 15;
        const int dq = lane >> 4;           // 0..3
        const float* xbl = xb + r;
        #pragma unroll
        for (int it = 0; it < 2; ++it) {
            int d0 = ((it * NW + w) * 4 + dq) * 8;      // 0..504, step 8
            float v[8];
            #pragma unroll
            for (int jj = 0; jj < 8; ++jj)
                v[jj] = xbl[(long)(d0 + jj) * TT];
            float4 lo = {v[0], v[1], v[2], v[3]};
            float4 hi = {v[4], v[5], v[6], v[7]};
            *reinterpret_cast<float4*>(&xsf[r * XLD + d0])     = lo;
            *reinterpret_cast<float4*>(&xsf[r * XLD + d0 + 4]) = hi;
        }
    }
    __syncthreads();                            // B1: x tile + inits ready

    // ---- GEMM: wave owns 128 codes (8 n-tiles), 1 m-tile (16 rows), K=512 ----
    f32x4 acc[8];
    #pragma unroll
    for (int n = 0; n < 8; ++n)
        acc[n] = (f32x4){0.f, 0.f, 0.f, 0.f};

    const short8v* Bhv = (const short8v*)Bph;
    {
        const int rl  = lane & 15;
        const int lg8 = (lane >> 4) * 8;
        for (int kk = 0; kk < 16; ++kk) {
            short8v ah = build_frag_rm(xsf + rl * XLD, kk * 32 + lg8);
            #pragma unroll
            for (int nh = 0; nh < 2; ++nh) {
                short8v bh[4];
                #pragma unroll
                for (int q = 0; q < 4; ++q)
                    bh[q] = Bhv[((w * 8 + nh * 4 + q) * 16 + kk) * 64 + lane];
                __builtin_amdgcn_s_setprio(1);
                #pragma unroll
                for (int q = 0; q < 4; ++q)
                    acc[nh * 4 + q] = __builtin_amdgcn_mfma_f32_16x16x32_bf16(
                        ah, bh[q], acc[nh * 4 + q], 0, 0, 0);
                __builtin_amdgcn_s_setprio(0);
            }
        }
    }

    // ---- epilogue: per-row wave-min -> LDS atomicMin(sortable) || pw ----
    float sef[8];
    #pragma unroll
    for (int n = 0; n < 8; ++n) sef[n] = se[w * 128 + n * 16 + (lane & 15)];

    #pragma unroll
    for (int r4 = 0; r4 < 4; ++r4) {
        float mn = 1e30f;
        #pragma unroll
        for (int n = 0; n < 8; ++n)
            mn = fminf(mn, fmaf(-2.f, acc[n][r4], sef[n]));
        #pragma unroll
        for (int off = 1; off < 16; off <<= 1)
            mn = fminf(mn, __shfl_xor(mn, off, 64));
        if ((lane & 15) == 0)
            atomicMin(&rowmin[(lane >> 4) * 4 + r4], f2sort(mn));
    }
    if (tid < 256) {   // pw: 16 rows x 16 threads, r12-verified numerics
        int r = tid >> 4, l = tid & 15;
        const float* bp = xsf + r * XLD;
        float pblk[4];
        #pragma unroll
        for (int kb = 0; kb < 4; ++kb) {
            float q[8];
            #pragma unroll
            for (int k = 0; k < 8; ++k) {
                float e = bp[kb * 128 + l + 16 * k];
                q[k] = __fmul_rn(e, e);
            }
            float V = __fadd_rn(__fadd_rn(__fadd_rn(q[0], q[1]), __fadd_rn(q[2], q[3])),
                                __fadd_rn(__fadd_rn(q[4], q[5]), __fadd_rn(q[6], q[7])));
            V = __fadd_rn(V, __shfl_xor(V, 8, 16));
            V = __fadd_rn(V, __shfl_xor(V, 4, 16));
            V = __fadd_rn(V, __shfl_xor(V, 2, 16));
            V = __fadd_rn(V, __shfl_xor(V, 1, 16));
            pblk[kb] = V;
        }
        if (l == 0)
            sxs[r] = __fadd_rn(__fadd_rn(pblk[0], pblk[1]), __fadd_rn(pblk[2], pblk[3]));
    }
    __syncthreads();                            // B2: rowmin + sxs final

    // ---- push candidates within margin ----
    #pragma unroll
    for (int r4 = 0; r4 < 4; ++r4) {
        int row = (lane >> 4) * 4 + r4;
        float th = sort2f(rowmin[row]) + MARGIN;
        #pragma unroll
        for (int n = 0; n < 8; ++n) {
            float sc = fmaf(-2.f, acc[n][r4], sef[n]);
            if (sc <= th) {
                int pos = atomicAdd(&rcnt[row], 1);
                if (pos < CM)
                    rc[row][pos] = (unsigned short)(w * 128 + n * 16 + (lane & 15));
            }
        }
    }
    __syncthreads();                            // B3: rc/rcnt final

    // ---- exact fp32 replay: static (row,slot) map, 96 slots over 8 waves ----
    if (lane < 12) {
        int s = lane * 8 + w;                   // 0..95
        int r = s / CM, ci = s - r * CM;
        int cnt = rcnt[r];
        if (cnt >= 2 && cnt <= CM && ci < cnt) {
            int c = (int)rc[r][ci];
            const float4* Ep4 = reinterpret_cast<const float4*>(E + (long)c * DD);
            const float4* Xp4 = reinterpret_cast<const float4*>(xsf + r * XLD);
            float g = 0.f;
            #pragma unroll 4
            for (int jj = 0; jj < 128; ++jj) {
                float4 e4 = Ep4[jj], x4 = Xp4[jj];
                g = __fmaf_rn(x4.x, e4.x, g);   // exact numpy order
                g = __fmaf_rn(x4.y, e4.y, g);
                g = __fmaf_rn(x4.z, e4.z, g);
                g = __fmaf_rn(x4.w, e4.w, g);
            }
            float t1 = __fadd_rn(sxs[r], se[c]);
            float d  = __fsub_rn(t1, __fmul_rn(2.f, g));
            unsigned long long key = ((unsigned long long)f2sort(d) << 10) | (unsigned int)c;
            atomicMin(&rmin[r], key);           // ties -> lower index (numpy)
        }
    }
    __syncthreads();                            // B4: rmin final

    // ---- resolve fidx ----
    if (tid < RWS) {
        int cnt = rcnt[tid];
        if (cnt == 1)                   fidx[tid] = (int)rc[tid][0];
        else if (cnt >= 2 && cnt <= CM) fidx[tid] = (int)(rmin[tid] & 0x3ffu);
        else { oflag[tid] = 1; atomicOr(&oany, 1); }
    }
    __syncthreads();                            // B5: fidx / oany visible

    // ---- overflow fallback (rare, uniform branch): 2 codes/thread replay ----
    if (oany) {
        for (int r = 0; r < RWS; ++r) {
            if (!oflag[r]) continue;
            const float4* Xp4 = reinterpret_cast<const float4*>(xsf + r * XLD);
            float bd = 1e30f; int bi = KK;
            #pragma unroll
            for (int q = 0; q < 2; ++q) {
                int c = q * BT + tid;           // ascending c => strict < keeps lowest
                const float4* Ep4 = reinterpret_cast<const float4*>(E + (long)c * DD);
                float g = 0.f;
                #pragma unroll 4
                for (int jj = 0; jj < 128; ++jj) {
                    float4 e4 = Ep4[jj], x4 = Xp4[jj];
                    g = __fmaf_rn(x4.x, e4.x, g);
                    g = __fmaf_rn(x4.y, e4.y, g);
                    g = __fmaf_rn(x4.z, e4.z, g);
                    g = __fmaf_rn(x4.w, e4.w, g);
                }
                float d = __fsub_rn(__fadd_rn(sxs[r], se[c]), __fmul_rn(2.f, g));
                if (d < bd) { bd = d; bi = c; }
            }
            #pragma unroll
            for (int off = 32; off; off >>= 1) {
                float tv = __shfl_down(bd, off, 64);
                int   ti = __shfl_down(bi, off, 64);
                if (tv < bd || (tv == bd && ti < bi)) { bd = tv; bi = ti; }
            }
            if (lane == 0) {
                unsigned long long key = ((unsigned long long)f2sort(bd) << 10) | (unsigned int)bi;
                atomicMin(&rmin[r], key);
            }
            __syncthreads();
            if (tid == 0) fidx[r] = (int)(rmin[r] & 0x3ffu);
            __syncthreads();
        }
        __syncthreads();
    }

    if (tid < RWS)
        out[(size_t)NN * DD + 1 + nbase + tid] = (float)fidx[tid];

    // ---- gather rows, quantized_st = fl(x + fl(q-x)), f32 loss accum ----
    float lacc = 0.f;
    #pragma unroll
    for (int it = 0; it < 4; ++it) {
        int flat = it * BT + tid;               // 2048 float4 = 16 rows * 128
        int r = flat >> 7;
        int j = (flat & 127) * 4;
        int idx = fidx[r];
        float4 ev = *reinterpret_cast<const float4*>(E + (long)idx * DD + j);
        float4 xv = *reinterpret_cast<const float4*>(&xsf[r * XLD + j]);
        float d0 = __fsub_rn(ev.x, xv.x);
        float d1 = __fsub_rn(ev.y, xv.y);
        float d2 = __fsub_rn(ev.z, xv.z);
        float d3 = __fsub_rn(ev.w, xv.w);
        float4 st;
        st.x = __fadd_rn(xv.x, d0); st.y = __fadd_rn(xv.y, d1);
        st.z = __fadd_rn(xv.z, d2); st.w = __fadd_rn(xv.w, d3);
        *reinterpret_cast<float4*>(out + (size_t)(nbase + r) * DD + j) = st;
        lacc = __fmaf_rn(d0, d0, lacc);
        lacc = __fmaf_rn(d1, d1, lacc);
        lacc = __fmaf_rn(d2, d2, lacc);
        lacc = __fmaf_rn(d3, d3, lacc);
    }
    double dl = (double)lacc;
    #pragma unroll
    for (int off = 32; off; off >>= 1) dl += __shfl_down(dl, off, 64);
    if (lane == 0) wloss[w] = dl;
    __syncthreads();
    if (tid == 0) {
        double s = 0.0;
        #pragma unroll
        for (int ww = 0; ww < NW; ++ww) s += wloss[ww];
        partials[blk] = s;                      // plain store, no atomic
    }
}

// ---------------- loss finalize: sum 4096 block partials ----------------
__global__ void finalize_kernel(const double* __restrict__ partials, float* __restrict__ out) {
    __shared__ double sm[16];
    const int tid = threadIdx.x;                // 1024 threads
    const int w = tid >> 6, lane = tid & 63;
    double a = 0.0;
    #pragma unroll
    for (int i = 0; i < NPART / 1024; ++i)
        a += partials[i * 1024 + tid];
    #pragma unroll
    for (int off = 32; off; off >>= 1) a += __shfl_down(a, off, 64);
    if (lane == 0) sm[w] = a;
    __syncthreads();
    if (tid == 0) {
        double s = 0.0;
        #pragma unroll
        for (int i = 0; i < 16; ++i) s += sm[i];
        out[(size_t)NN * DD] = (float)(1.25 * s / ((double)NN * DD));
    }
}

extern "C" void kernel_launch(void* const* d_in, const int* in_sizes, int n_in,
                              void* d_out, int out_size, void* d_ws, size_t ws_size,
                              hipStream_t stream) {
    const float* x = (const float*)d_in[0];
    const float* E = (const float*)d_in[1];
    float* out = (float*)d_out;
    double* partials = (double*)d_ws;                                   // 32 KB
    float* se = (float*)((char*)d_ws + 32768);                          // 4 KB
    unsigned short* Bph = (unsigned short*)((char*)d_ws + 65536);       // 1 MB

    enorms_exact<<<4, 256, 0, stream>>>(E, se);
    pack_e<<<(KK * DD / 2) / 256, 256, 0, stream>>>(E, Bph);
    vq_fused<<<NPART, BT, 0, stream>>>(x, E, Bph, se, partials, out);
    finalize_kernel<<<1, 1024, 0, stream>>>(partials, out);
}

// Round 19
// 207.268 us; speedup vs baseline: 1.3327x; 1.3327x over previous
//
#include <hip/hip_runtime.h>

#define BB 16
#define DD 512
#define TT 4096
#define KK 1024
#define NN (BB*TT)              // 65536 rows
#define RWS 32                  // rows per block (measured optimum: r13=64:270, r16=32:208, r18=16:276)
#define BT 512                  // 8 waves
#define NW 8
#define MARGIN 1e-3f            // candidate margin (req <=8e-4, 25% slack)
#define CM 6                    // candidate slots per row
#define XLD 516                 // floats per x row (2064 B, 16B-aligned)
#define NPART (NN/RWS)          // 2048 partials

typedef __attribute__((ext_vector_type(8))) short short8v;   // 8 bf16
typedef __attribute__((ext_vector_type(4))) float f32x4;

// ---- bf16 helper (RNE) ----
__device__ __forceinline__ unsigned short f2bf(float f) {
    unsigned int u = __float_as_uint(f);
    unsigned int r = (u + 0x7fffu + ((u >> 16) & 1u)) >> 16;
    return (unsigned short)r;
}

// ---- sortable-float mapping (monotone: f1<f2 <=> u1<u2) ----
__device__ __forceinline__ unsigned int f2sort(float f) {
    unsigned int b = __float_as_uint(f);
    return (b & 0x80000000u) ? ~b : (b | 0x80000000u);
}
__device__ __forceinline__ float sort2f(unsigned int u) {
    unsigned int b = (u & 0x80000000u) ? (u & 0x7fffffffu) : ~u;
    return __uint_as_float(b);
}

// ---- numpy pairwise-sum replication (fp32, squares) — verified passing ----
__device__ __forceinline__ float pw128_sq_strided(const float* a, int stride) {
    float V[16];
    #pragma unroll
    for (int l = 0; l < 16; ++l) {
        float q[8];
        #pragma unroll
        for (int k = 0; k < 8; ++k) {
            float e = a[(l + 16 * k) * stride];
            q[k] = __fmul_rn(e, e);
        }
        V[l] = __fadd_rn(__fadd_rn(__fadd_rn(q[0], q[1]), __fadd_rn(q[2], q[3])),
                         __fadd_rn(__fadd_rn(q[4], q[5]), __fadd_rn(q[6], q[7])));
    }
    float u[8];
    #pragma unroll
    for (int l = 0; l < 8; ++l) u[l] = __fadd_rn(V[l], V[l + 8]);
    float v[4];
    #pragma unroll
    for (int l = 0; l < 4; ++l) v[l] = __fadd_rn(u[l], u[l + 4]);
    return __fadd_rn(__fadd_rn(v[0], v[2]), __fadd_rn(v[1], v[3]));
}
__device__ __forceinline__ float pw512_sq_strided(const float* a, int stride) {
    float p0 = pw128_sq_strided(a, stride);
    float p1 = pw128_sq_strided(a + 128 * stride, stride);
    float p2 = pw128_sq_strided(a + 256 * stride, stride);
    float p3 = pw128_sq_strided(a + 384 * stride, stride);
    return __fadd_rn(__fadd_rn(p0, p1), __fadd_rn(p2, p3));
}

// ---------------- exact ||e||^2 per code row ----------------
__global__ void enorms_exact(const float* __restrict__ E, float* __restrict__ se) {
    int i = blockIdx.x * blockDim.x + threadIdx.x;
    if (i < KK) se[i] = pw512_sq_strided(E + (long)i * DD, 1);
}

// ---------------- pack E (hi bf16) into MFMA B-fragment layout (u32 pairs) --
__global__ void pack_e(const float* __restrict__ E, unsigned short* __restrict__ Bph) {
    int i = blockIdx.x * blockDim.x + threadIdx.x;   // 0 .. KK*DD/2-1
    if (i >= KK * DD / 2) return;
    int c = i >> 8;
    int k = (i & 255) * 2;
    float2 v = *reinterpret_cast<const float2*>(E + ((long)c << 9) + k);
    int lane = (c & 15) + ((k >> 3) & 3) * 16;
    int hw = (((c >> 4) * 16 + (k >> 5)) * 64 + lane) * 8 + (k & 7);
    unsigned int pk = (unsigned int)f2bf(v.x) | ((unsigned int)f2bf(v.y) << 16);
    *reinterpret_cast<unsigned int*>(Bph + hw) = pk;
}

// ---- build bf16-hi A fragment from row-major f32 LDS row (r5/r13-verified) ----
__device__ __forceinline__ short8v build_frag_rm(const float* __restrict__ row, int c0) {
    union { short8v v; unsigned int wd[4]; } u;
    float4 a = *reinterpret_cast<const float4*>(row + c0);
    float4 b = *reinterpret_cast<const float4*>(row + c0 + 4);
    asm("v_cvt_pk_bf16_f32 %0, %1, %2" : "=v"(u.wd[0]) : "v"(a.x), "v"(a.y));
    asm("v_cvt_pk_bf16_f32 %0, %1, %2" : "=v"(u.wd[1]) : "v"(a.z), "v"(a.w));
    asm("v_cvt_pk_bf16_f32 %0, %1, %2" : "=v"(u.wd[2]) : "v"(b.x), "v"(b.y));
    asm("v_cvt_pk_bf16_f32 %0, %1, %2" : "=v"(u.wd[3]) : "v"(b.z), "v"(b.w));
    return u.v;
}

// =============== fused (2 blocks/CU, 5 barriers common path) ===============
__global__ __launch_bounds__(BT)
void vq_fused(const float* __restrict__ x, const float* __restrict__ E,
              const unsigned short* __restrict__ Bph,
              const float* __restrict__ se,
              double* __restrict__ partials, float* __restrict__ out) {
    __shared__ __align__(16) float xsf[RWS * XLD];   // 66,048 B row-major [r][d]
    __shared__ unsigned int rowmin[RWS];             // sortable-bits global row min
    __shared__ int   rcnt[RWS];
    __shared__ unsigned short rc[RWS][CM];
    __shared__ unsigned long long rmin[RWS];
    __shared__ float sxs[RWS];
    __shared__ int   fidx[RWS];
    __shared__ int   oflag[RWS];
    __shared__ double wloss[NW];
    __shared__ int   oany;

    const int tid  = threadIdx.x;
    const int w    = tid >> 6;              // 0..7
    const int lane = tid & 63;
    const int blk  = blockIdx.x;
    const int b    = blk >> 7;              // 128 blocks per batch
    const int t0   = (blk & 127) * RWS;
    const long nbase = (long)b * TT + t0;
    const float* xb = x + (long)b * DD * TT + t0;

    if (tid < RWS) {
        rcnt[tid] = 0; rowmin[tid] = 0xFFFFFFFFu; rmin[tid] = ~0ull;
        oflag[tid] = 0; fidx[tid] = -1;
    }
    if (tid == 0) oany = 0;

    // ---- stage (r14-proven): dword loads (lane&31 = row), float4 LDS writes ----
    {
        const int r  = lane & 31;
        const int dh = lane >> 5;           // 0/1
        const float* xbl = xb + r;
        #pragma unroll
        for (int it = 0; it < 4; ++it) {
            int d0 = ((it * NW + w) * 2 + dh) * 8;      // 0..504, step 8
            float v[8];
            #pragma unroll
            for (int jj = 0; jj < 8; ++jj)
                v[jj] = xbl[(long)(d0 + jj) * TT];
            float4 lo = {v[0], v[1], v[2], v[3]};
            float4 hi = {v[4], v[5], v[6], v[7]};
            *reinterpret_cast<float4*>(&xsf[r * XLD + d0])     = lo;
            *reinterpret_cast<float4*>(&xsf[r * XLD + d0 + 4]) = hi;
        }
    }
    __syncthreads();                            // B1: x tile + inits ready

    // ---- GEMM: wave owns 128 codes (8 n-tiles), 2 m-tiles, K=512 ----
    f32x4 acc[2][8];
    #pragma unroll
    for (int m = 0; m < 2; ++m)
        #pragma unroll
        for (int n = 0; n < 8; ++n)
            acc[m][n] = (f32x4){0.f, 0.f, 0.f, 0.f};

    const short8v* Bhv = (const short8v*)Bph;
    {
        const int rl  = lane & 15;
        const int lg8 = (lane >> 4) * 8;
        for (int kk = 0; kk < 16; ++kk) {
            short8v ah[2];
            #pragma unroll
            for (int m = 0; m < 2; ++m)
                ah[m] = build_frag_rm(xsf + (m * 16 + rl) * XLD, kk * 32 + lg8);
            #pragma unroll
            for (int nh = 0; nh < 2; ++nh) {
                short8v bh[4];
                #pragma unroll
                for (int q = 0; q < 4; ++q)
                    bh[q] = Bhv[((w * 8 + nh * 4 + q) * 16 + kk) * 64 + lane];
                __builtin_amdgcn_s_setprio(1);
                #pragma unroll
                for (int q = 0; q < 4; ++q)
                    #pragma unroll
                    for (int m = 0; m < 2; ++m)
                        acc[m][nh * 4 + q] = __builtin_amdgcn_mfma_f32_16x16x32_bf16(
                            ah[m], bh[q], acc[m][nh * 4 + q], 0, 0, 0);
                __builtin_amdgcn_s_setprio(0);
            }
        }
    }

    // ---- epilogue: per-row wave-min -> LDS atomicMin(sortable) || pw ----
    float sef[8];
    #pragma unroll
    for (int n = 0; n < 8; ++n) sef[n] = se[w * 128 + n * 16 + (lane & 15)];

    #pragma unroll
    for (int m = 0; m < 2; ++m) {
        #pragma unroll
        for (int r4 = 0; r4 < 4; ++r4) {
            float mn = 1e30f;
            #pragma unroll
            for (int n = 0; n < 8; ++n)
                mn = fminf(mn, fmaf(-2.f, acc[m][n][r4], sef[n]));
            #pragma unroll
            for (int off = 1; off < 16; off <<= 1)
                mn = fminf(mn, __shfl_xor(mn, off, 64));
            if ((lane & 15) == 0)
                atomicMin(&rowmin[m * 16 + (lane >> 4) * 4 + r4], f2sort(mn));
        }
    }
    {   // pw: r = tid>>4 (32 rows x 16 threads), r12-verified numerics
        int r = tid >> 4, l = tid & 15;
        const float* bp = xsf + r * XLD;
        float pblk[4];
        #pragma unroll
        for (int kb = 0; kb < 4; ++kb) {
            float q[8];
            #pragma unroll
            for (int k = 0; k < 8; ++k) {
                float e = bp[kb * 128 + l + 16 * k];
                q[k] = __fmul_rn(e, e);
            }
            float V = __fadd_rn(__fadd_rn(__fadd_rn(q[0], q[1]), __fadd_rn(q[2], q[3])),
                                __fadd_rn(__fadd_rn(q[4], q[5]), __fadd_rn(q[6], q[7])));
            V = __fadd_rn(V, __shfl_xor(V, 8, 16));
            V = __fadd_rn(V, __shfl_xor(V, 4, 16));
            V = __fadd_rn(V, __shfl_xor(V, 2, 16));
            V = __fadd_rn(V, __shfl_xor(V, 1, 16));
            pblk[kb] = V;
        }
        if (l == 0)
            sxs[r] = __fadd_rn(__fadd_rn(pblk[0], pblk[1]), __fadd_rn(pblk[2], pblk[3]));
    }
    __syncthreads();                            // B2: rowmin + sxs final

    // ---- push candidates within margin (threshold read inline) ----
    #pragma unroll
    for (int m = 0; m < 2; ++m) {
        #pragma unroll
        for (int r4 = 0; r4 < 4; ++r4) {
            int row = m * 16 + (lane >> 4) * 4 + r4;
            float th = sort2f(rowmin[row]) + MARGIN;
            #pragma unroll
            for (int n = 0; n < 8; ++n) {
                float sc = fmaf(-2.f, acc[m][n][r4], sef[n]);
                if (sc <= th) {
                    int pos = atomicAdd(&rcnt[row], 1);
                    if (pos < CM)
                        rc[row][pos] = (unsigned short)(w * 128 + n * 16 + (lane & 15));
                }
            }
        }
    }
    __syncthreads();                            // B3: rc/rcnt final

    // ---- exact fp32 replay: static (row,slot) -> thread map, no pair list ----
    if (lane < 24) {
        int s = lane * 8 + w;                   // 0..191 spread across waves
        int r = s / CM, ci = s - r * CM;
        int cnt = rcnt[r];
        if (cnt >= 2 && cnt <= CM && ci < cnt) {
            int c = (int)rc[r][ci];
            const float4* Ep4 = reinterpret_cast<const float4*>(E + (long)c * DD);
            const float4* Xp4 = reinterpret_cast<const float4*>(xsf + r * XLD);
            float g = 0.f;
            #pragma unroll 4
            for (int jj = 0; jj < 128; ++jj) {
                float4 e4 = Ep4[jj], x4 = Xp4[jj];
                g = __fmaf_rn(x4.x, e4.x, g);   // exact numpy order
                g = __fmaf_rn(x4.y, e4.y, g);
                g = __fmaf_rn(x4.z, e4.z, g);
                g = __fmaf_rn(x4.w, e4.w, g);
            }
            float t1 = __fadd_rn(sxs[r], se[c]);
            float d  = __fsub_rn(t1, __fmul_rn(2.f, g));
            unsigned long long key = ((unsigned long long)f2sort(d) << 10) | (unsigned int)c;
            atomicMin(&rmin[r], key);           // ties -> lower index (numpy)
        }
    }
    __syncthreads();                            // B4: rmin final

    // ---- resolve fidx ----
    if (tid < RWS) {
        int cnt = rcnt[tid];
        if (cnt == 1)                   fidx[tid] = (int)rc[tid][0];
        else if (cnt >= 2 && cnt <= CM) fidx[tid] = (int)(rmin[tid] & 0x3ffu);
        else { oflag[tid] = 1; atomicOr(&oany, 1); }   // overflow (or impossible 0)
    }
    __syncthreads();                            // B5: fidx / oany visible

    // ---- overflow fallback (rare, uniform branch): 2 codes/thread replay ----
    if (oany) {
        for (int r = 0; r < RWS; ++r) {
            if (!oflag[r]) continue;            // LDS-uniform branch
            const float4* Xp4 = reinterpret_cast<const float4*>(xsf + r * XLD);
            float bd = 1e30f; int bi = KK;
            #pragma unroll
            for (int q = 0; q < 2; ++q) {
                int c = q * BT + tid;           // ascending c => strict < keeps lowest
                const float4* Ep4 = reinterpret_cast<const float4*>(E + (long)c * DD);
                float g = 0.f;
                #pragma unroll 4
                for (int jj = 0; jj < 128; ++jj) {
                    float4 e4 = Ep4[jj], x4 = Xp4[jj];
                    g = __fmaf_rn(x4.x, e4.x, g);
                    g = __fmaf_rn(x4.y, e4.y, g);
                    g = __fmaf_rn(x4.z, e4.z, g);
                    g = __fmaf_rn(x4.w, e4.w, g);
                }
                float d = __fsub_rn(__fadd_rn(sxs[r], se[c]), __fmul_rn(2.f, g));
                if (d < bd) { bd = d; bi = c; }
            }
            #pragma unroll
            for (int off = 32; off; off >>= 1) {
                float tv = __shfl_down(bd, off, 64);
                int   ti = __shfl_down(bi, off, 64);
                if (tv < bd || (tv == bd && ti < bi)) { bd = tv; bi = ti; }
            }
            if (lane == 0) {
                unsigned long long key = ((unsigned long long)f2sort(bd) << 10) | (unsigned int)bi;
                atomicMin(&rmin[r], key);
            }
            __syncthreads();
            if (tid == 0) fidx[r] = (int)(rmin[r] & 0x3ffu);
            __syncthreads();
        }
        __syncthreads();                        // publish overflow fidx
    }

    if (tid < RWS)
        out[(size_t)NN * DD + 1 + nbase + tid] = (float)fidx[tid];

    // ---- gather rows, quantized_st = fl(x + fl(q-x)), f32 loss accum ----
    float lacc = 0.f;
    #pragma unroll
    for (int it = 0; it < 8; ++it) {
        int flat = it * BT + tid;               // 4096 float4 = 32 rows * 128
        int r = flat >> 7;
        int j = (flat & 127) * 4;
        int idx = fidx[r];
        float4 ev = *reinterpret_cast<const float4*>(E + (long)idx * DD + j);
        float4 xv = *reinterpret_cast<const float4*>(&xsf[r * XLD + j]);
        float d0 = __fsub_rn(ev.x, xv.x);
        float d1 = __fsub_rn(ev.y, xv.y);
        float d2 = __fsub_rn(ev.z, xv.z);
        float d3 = __fsub_rn(ev.w, xv.w);
        float4 st;
        st.x = __fadd_rn(xv.x, d0); st.y = __fadd_rn(xv.y, d1);
        st.z = __fadd_rn(xv.z, d2); st.w = __fadd_rn(xv.w, d3);
        *reinterpret_cast<float4*>(out + (size_t)(nbase + r) * DD + j) = st;
        lacc = __fmaf_rn(d0, d0, lacc);
        lacc = __fmaf_rn(d1, d1, lacc);
        lacc = __fmaf_rn(d2, d2, lacc);
        lacc = __fmaf_rn(d3, d3, lacc);
    }
    double dl = (double)lacc;
    #pragma unroll
    for (int off = 32; off; off >>= 1) dl += __shfl_down(dl, off, 64);
    if (lane == 0) wloss[w] = dl;
    __syncthreads();
    if (tid == 0) {
        double s = 0.0;
        #pragma unroll
        for (int ww = 0; ww < NW; ++ww) s += wloss[ww];
        partials[blk] = s;                      // plain store, no atomic
    }
}

// ---------------- loss finalize: sum 2048 block partials ----------------
__global__ void finalize_kernel(const double* __restrict__ partials, float* __restrict__ out) {
    __shared__ double sm[16];
    const int tid = threadIdx.x;                // 1024 threads
    const int w = tid >> 6, lane = tid & 63;
    double a = partials[tid] + partials[tid + 1024];
    #pragma unroll
    for (int off = 32; off; off >>= 1) a += __shfl_down(a, off, 64);
    if (lane == 0) sm[w] = a;
    __syncthreads();
    if (tid == 0) {
        double s = 0.0;
        #pragma unroll
        for (int i = 0; i < 16; ++i) s += sm[i];
        out[(size_t)NN * DD] = (float)(1.25 * s / ((double)NN * DD));
    }
}

extern "C" void kernel_launch(void* const* d_in, const int* in_sizes, int n_in,
                              void* d_out, int out_size, void* d_ws, size_t ws_size,
                              hipStream_t stream) {
    const float* x = (const float*)d_in[0];
    const float* E = (const float*)d_in[1];
    float* out = (float*)d_out;
    double* partials = (double*)d_ws;                                   // 16 KB
    float* se = (float*)((char*)d_ws + 32768);                          // 4 KB
    unsigned short* Bph = (unsigned short*)((char*)d_ws + 65536);       // 1 MB

    enorms_exact<<<4, 256, 0, stream>>>(E, se);
    pack_e<<<(KK * DD / 2) / 256, 256, 0, stream>>>(E, Bph);
    vq_fused<<<NPART, BT, 0, stream>>>(x, E, Bph, se, partials, out);
    finalize_kernel<<<1, 1024, 0, stream>>>(partials, out);
}